// Round 15
// baseline (209.074 us; speedup 1.0000x reference)
//
#include <hip/hip_runtime.h>
#include <hip/hip_bf16.h>
#include <cstddef>
#include <cstdint>

#define N_NODES 2048
#define E_EDGES 131072
#define IN_DIM  512
#define HID     2048
#define NCLS    16

typedef __bf16 bf16x8 __attribute__((ext_vector_type(8)));
typedef short  s16x4  __attribute__((ext_vector_type(4)));
typedef short  s16x8  __attribute__((ext_vector_type(8)));
typedef float  f32x4  __attribute__((ext_vector_type(4)));

__device__ __forceinline__ unsigned short f2bf(float f) {
  unsigned u = __builtin_bit_cast(unsigned, f);
  u = (u + 0x7FFFu + ((u >> 16) & 1u)) >> 16;
  return (unsigned short)u;
}
__device__ __forceinline__ float bf2f(short h) {
  unsigned u = (unsigned)(unsigned short)h << 16;
  return __builtin_bit_cast(float, u);
}

// K-permutation within each 32-col block: lane g's 8-elem MFMA fragment
// (k = g*4+{0..3}, g*4+16+{0..3}) becomes contiguous slots [8g,8g+8) -> one
// ds_read_b128 per fragment. pos32 is a bit 3-cycle; inverse = pos32 twice.
__device__ __forceinline__ int pos32(int k) {
  return (((k >> 2) & 3) << 3) | (((k >> 4) & 1) << 2) | (k & 3);
}

#define GLD16(gp, lp) __builtin_amdgcn_global_load_lds(                     \
    (__attribute__((address_space(1))) void*)(gp),                          \
    (__attribute__((address_space(3))) void*)(lp), 16, 0, 0)

// ---------------------------------------------------------------------------
// Dense adjacency build; columns stored K-PERMUTED (perm folded into atomics).
// ---------------------------------------------------------------------------
__global__ void build_adj_kernel(const int* __restrict__ src, const int* __restrict__ dst,
                                 float* __restrict__ adj) {
  int e = blockIdx.x * blockDim.x + threadIdx.x;
  if (e < E_EDGES) {
    int s = src[e], d = dst[e];
    int sp = (s & ~31) | pos32(s & 31);
    atomicAdd(&adj[(size_t)d * N_NODES + sp], 1.0f);
  }
}

// ---------------------------------------------------------------------------
// Fused operand prep; adj-cvt blocks also accumulate per-row degree sums
// (exact integer fp32 partials, commutative -> deterministic).
// ---------------------------------------------------------------------------
__global__ __launch_bounds__(256) void prep_kernel(
    const float* __restrict__ adjf, short* __restrict__ adjb,
    float* __restrict__ rsums,
    const float* __restrict__ x,   short* __restrict__ xb,   short* __restrict__ xT,
    const float* __restrict__ W1l, short* __restrict__ W1lT,
    const float* __restrict__ W1r, short* __restrict__ W1rT,
    const float* __restrict__ W2l, short* __restrict__ W2lT,
    const float* __restrict__ W2r, short* __restrict__ W2rT)
{
  int bid = blockIdx.x, tid = threadIdx.x;
  if (bid < 4096) {                         // adj cvt (plain layout) + row sums
    size_t flat = ((size_t)bid * 256 + tid) * 4;
    float4 v = *reinterpret_cast<const float4*>(&adjf[flat]);
    s16x4 o;
    o[0] = (short)f2bf(v.x); o[1] = (short)f2bf(v.y);
    o[2] = (short)f2bf(v.z); o[3] = (short)f2bf(v.w);
    *reinterpret_cast<s16x4*>(&adjb[flat]) = o;
    float ls = v.x + v.y + v.z + v.w;       // counts: exact in fp32
#pragma unroll
    for (int off = 32; off; off >>= 1) ls += __shfl_down(ls, off);
    __shared__ float wred[4];
    if ((tid & 63) == 0) wred[tid >> 6] = ls;
    __syncthreads();
    if (tid == 0)
      atomicAdd(&rsums[bid >> 1], wred[0] + wred[1] + wred[2] + wred[3]);
    return;
  }
  bid -= 4096;
  if (bid < 1024) {                         // x cvt, perm slots
    size_t flat = ((size_t)bid * 256 + tid) * 4;
    float4 v = *reinterpret_cast<const float4*>(&x[flat]);
    s16x4 o;
    o[0] = (short)f2bf(v.x); o[1] = (short)f2bf(v.y);
    o[2] = (short)f2bf(v.z); o[3] = (short)f2bf(v.w);
    size_t base = (flat & ~(size_t)31) | (size_t)pos32((int)(flat & 31));
    *reinterpret_cast<s16x4*>(&xb[base]) = o;
    return;
  }
  bid -= 1024;
  __shared__ float t[32][33];
  const float* in; short* outp; int R, C, bx, by;
  if (bid < 1024)      { in = x;   outp = xT;   R = N_NODES; C = IN_DIM; bx = bid & 15; by = bid >> 4; }
  else if (bid < 2048) { bid -= 1024; in = W1l; outp = W1lT; R = IN_DIM; C = HID; bx = bid & 63; by = bid >> 6; }
  else if (bid < 3072) { bid -= 2048; in = W1r; outp = W1rT; R = IN_DIM; C = HID; bx = bid & 63; by = bid >> 6; }
  else if (bid < 7168) { bid -= 3072; in = W2l; outp = W2lT; R = HID;    C = HID; bx = bid & 63; by = bid >> 6; }
  else                 { bid -= 7168; in = W2r; outp = W2rT; R = HID;    C = HID; bx = bid & 63; by = bid >> 6; }
  int c0 = bx * 32, r0 = by * 32;
  int tx = tid & 31, ty = tid >> 5;
#pragma unroll
  for (int i = 0; i < 4; ++i)
    t[ty + 8 * i][tx] = in[(size_t)(r0 + ty + 8 * i) * C + c0 + tx];
  __syncthreads();
  int ip = pos32(pos32(tx));   // inverse perm
#pragma unroll
  for (int i = 0; i < 4; ++i)
    outp[(size_t)(c0 + ty + 8 * i) * R + r0 + tx] = (short)f2bf(t[ip][ty + 8 * i]);
}

// ---------------------------------------------------------------------------
// 256x256 bf16 MFMA GEMM, 2-buffer LDS (64 KB) -> 2 blocks/CU co-resident.
// 512 threads = 8 waves (2M x 4N), wave-tile 128x64, BK=32.
// Schedule (R5-verified pattern at 256^2): STAGE(0); sync; loop t:
// {STAGE(t+1, buf^1); ds_read+MFMA(t); __syncthreads (implicit vmcnt(0)
// drains AFTER compute; other co-resident block covers the drain)}.
// Race ledger: buf^1's last readers finished at the t-1 barrier; reads of
// buf at iter t are protected by the t-1 barrier's vmcnt(0) drain.
// Coalesced epilogue in 2 passes of 4 slabs (64 KB): full-line stores.
// XCD-aware 1D decode, bf16 partials (unchanged from R14).
// ---------------------------------------------------------------------------
__global__ __launch_bounds__(512) void gemm256(
    const short* __restrict__ A1, const short* __restrict__ B1, int K1,
    const short* __restrict__ A2, const short* __restrict__ B2, int K2,
    int nz, int gx, short* __restrict__ P, int M, int N)
{
  __shared__ short As[2][256 * 32];   // 2 x 16 KB
  __shared__ short Bs[2][256 * 32];   // 2 x 16 KB  (64 KB total)

  const int tid = threadIdx.x, wid = tid >> 6, lane = tid & 63;
  const int g = lane >> 4, r16 = lane & 15;
  const int wm = (wid >> 2) * 128, wn = (wid & 3) * 64;

  // XCD-aware decode (HW maps block L -> XCD L%8)
  const int L = blockIdx.x;
  const int xcd = L & 7, w = L >> 3;
  int bnI, byI, z;
  if (gx == 8) { z = xcd >> 1; bnI = w & 7; byI = ((xcd & 1) << 2) + (w >> 3); }
  else         { bnI = (w >> 1) & 1; byI = w >> 2; z = xcd * 2 + (w & 1); }
  const int bm = byI * 256, bn = bnI * 256;

  const int s1  = K1 / nz / 32;
  const int s2  = A2 ? K2 / nz / 32 : 0;
  const int k01 = z * (K1 / nz);
  const int k02 = A2 ? z * (K2 / nz) : 0;
  const int total = s1 + s2;
  short* Pz = P + (size_t)z * M * N;

  auto SRC = [&](int t, const short*& A, const short*& B, int& lda, int& k) {
    if (t < s1) { A = A1; B = B1; lda = K1; k = k01 + t * 32; }
    else        { A = A2; B = B2; lda = K2; k = k02 + (t - s1) * 32; }
  };
  auto STAGE = [&](int t) {
    const short* A; const short* B; int lda, k;
    SRC(t, A, B, lda, k);
    int buf = t & 1;
#pragma unroll
    for (int h = 0; h < 2; ++h) {
      int Pl = h * 512 + tid;               // 0..1023 (16B units)
      int m = Pl >> 2, U = Pl & 3;
      int v = U ^ ((m >> 1) & 3);
      GLD16(A + (size_t)(bm + m) * lda + k + v * 8, &As[buf][(h * 512 + wid * 64) * 8]);
    }
#pragma unroll
    for (int h = 0; h < 2; ++h) {
      int Pl = h * 512 + tid;
      int n = Pl >> 2, U = Pl & 3;
      int v = U ^ ((n >> 1) & 3);
      GLD16(B + (size_t)(bn + n) * lda + k + v * 8, &Bs[buf][(h * 512 + wid * 64) * 8]);
    }
  };

  f32x4 acc[8][4];
#pragma unroll
  for (int mi = 0; mi < 8; ++mi)
#pragma unroll
    for (int ni = 0; ni < 4; ++ni)
#pragma unroll
      for (int r = 0; r < 4; ++r) acc[mi][ni][r] = 0.0f;

  bf16x8 bfr[4];
  auto READ_B = [&](int buf) {
#pragma unroll
    for (int ni = 0; ni < 4; ++ni) {
      int n = wn + ni * 16 + r16;
      bfr[ni] = __builtin_bit_cast(bf16x8, *(const s16x8*)&Bs[buf][n * 32 + ((g ^ ((n >> 1) & 3)) << 3)]);
    }
  };
  bf16x8 afr[4];
  auto READ_A = [&](int buf, int mlo) {
#pragma unroll
    for (int i = 0; i < 4; ++i) {
      int m = wm + (mlo + i) * 16 + r16;
      afr[i] = __builtin_bit_cast(bf16x8, *(const s16x8*)&As[buf][m * 32 + ((g ^ ((m >> 1) & 3)) << 3)]);
    }
  };
  auto MMA = [&](int mlo) {
    __builtin_amdgcn_s_setprio(1);
#pragma unroll
    for (int i = 0; i < 4; ++i)
#pragma unroll
      for (int ni = 0; ni < 4; ++ni)
        acc[mlo + i][ni] = __builtin_amdgcn_mfma_f32_16x16x32_bf16(afr[i], bfr[ni], acc[mlo + i][ni], 0, 0, 0);
    __builtin_amdgcn_s_setprio(0);
  };

  STAGE(0);
  __syncthreads();                     // tile 0 resident (implicit vmcnt(0))

#pragma unroll 1
  for (int t = 0; t < total; ++t) {
    const int buf = t & 1;
    if (t + 1 < total) STAGE(t + 1);   // issue next tile into buf^1
    READ_B(buf); READ_A(buf, 0);
    MMA(0);
    READ_A(buf, 4);
    MMA(4);
    __syncthreads();                   // drains vmcnt(0): next tile resident;
  }                                    // all waves done reading buf

  // ---- coalesced epilogue: 2 passes of 4 slabs (64 KB each) ----
  {
    const int rlb = (wid >> 2) * 16 + g * 4;      // slab-local row base
    const int rr2 = tid >> 4;                     // 0..31 (write pass row)
    const int growbase = bm + ((rr2 & 16) << 3) + (rr2 & 15);
    const int sw = ((rr2 >> 2) & 3) << 4;
#pragma unroll
    for (int pass = 0; pass < 2; ++pass) {
      __builtin_amdgcn_s_barrier();              // LDS free / prev pass done
#pragma unroll
      for (int j = 0; j < 4; ++j) {
        int mi = pass * 4 + j;
        short* slabp = (j < 2) ? &As[j][0] : &Bs[j - 2][0];
#pragma unroll
        for (int ni = 0; ni < 4; ++ni) {
          int c = wn + ni * 16 + r16;
#pragma unroll
          for (int r = 0; r < 4; ++r) {
            int rr = rlb + r;                     // 0..31
            int cp = c ^ (((rr >> 2) & 3) << 4);  // bank swizzle
            slabp[rr * 256 + cp] = (short)f2bf(acc[mi][ni][r]);
          }
        }
      }
      __builtin_amdgcn_s_barrier();
#pragma unroll
      for (int j = 0; j < 4; ++j) {
        int mi = pass * 4 + j;
        const short* slabp = (j < 2) ? &As[j][0] : &Bs[j - 2][0];
        size_t rowoff = (size_t)(growbase + mi * 16) * N + bn;
#pragma unroll
        for (int p = 0; p < 2; ++p) {
          int cbase = ((tid & 15) + p * 16) * 8;  // logical col, 8-aligned
          s16x8 v = *(const s16x8*)&slabp[rr2 * 256 + (cbase ^ sw)];
          *reinterpret_cast<s16x8*>(&Pz[rowoff + cbase]) = v;
        }
      }
    }
  }
}

// ---------------------------------------------------------------------------
// Combine bf16 z-partials: sum, optional 1/max(rsums[row],1) scale, bias,
// relu; write fp32 plain and/or bf16 (K-permuted if permB, else plain).
// ---------------------------------------------------------------------------
__global__ __launch_bounds__(256) void combine_kernel(
    const short* P, int nz, size_t MN,
    const float* rsums, int rshift,
    const float* bias, int cmask, int doRelu,
    short* outb, int permB, float* outf)
{
  size_t flat = ((size_t)blockIdx.x * 256 + threadIdx.x) * 4;
  if (flat >= MN) return;
  s16x4 t4 = *reinterpret_cast<const s16x4*>(&P[flat]);
  float4 s = make_float4(bf2f(t4[0]), bf2f(t4[1]), bf2f(t4[2]), bf2f(t4[3]));
#pragma unroll 1
  for (int zz = 1; zz < nz; ++zz) {
    s16x4 u4 = *reinterpret_cast<const s16x4*>(&P[(size_t)zz * MN + flat]);
    s.x += bf2f(u4[0]); s.y += bf2f(u4[1]); s.z += bf2f(u4[2]); s.w += bf2f(u4[3]);
  }
  if (rsums) {
    float sc = 1.0f / fmaxf(rsums[flat >> rshift], 1.0f);
    s.x *= sc; s.y *= sc; s.z *= sc; s.w *= sc;
  }
  if (bias) {
    float4 bv = *reinterpret_cast<const float4*>(&bias[flat & (size_t)cmask]);
    s.x += bv.x; s.y += bv.y; s.z += bv.z; s.w += bv.w;
  }
  if (doRelu) {
    s.x = fmaxf(s.x, 0.0f); s.y = fmaxf(s.y, 0.0f);
    s.z = fmaxf(s.z, 0.0f); s.w = fmaxf(s.w, 0.0f);
  }
  if (outf) *reinterpret_cast<float4*>(&outf[flat]) = s;
  if (outb) {
    s16x4 o;
    o[0] = (short)f2bf(s.x); o[1] = (short)f2bf(s.y);
    o[2] = (short)f2bf(s.z); o[3] = (short)f2bf(s.w);
    size_t base = permB ? ((flat & ~(size_t)31) | (size_t)pos32((int)(flat & 31)))
                        : flat;
    *reinterpret_cast<s16x4*>(&outb[base]) = o;
  }
}

// ---------------------------------------------------------------------------
// x1 finisher: sum nz bf16 partials + bias + relu, write x1b (bf16, perm
// cols) AND x1T (bf16, transposed, perm slots). Grid (HID/32, N/32).
// ---------------------------------------------------------------------------
__global__ __launch_bounds__(256) void combine_tr_kernel(
    const short* __restrict__ P, int nz,
    const float* __restrict__ bias,
    short* __restrict__ xn, short* __restrict__ xnT)
{
  __shared__ float t[32][33];
  const size_t MN = (size_t)N_NODES * HID;
  int c0 = blockIdx.x * 32, r0 = blockIdx.y * 32;
  int tx = threadIdx.x & 31, ty = threadIdx.x >> 5;
  int colp = c0 + pos32(tx);
#pragma unroll
  for (int i = 0; i < 4; ++i) {
    int row = r0 + ty + 8 * i;
    size_t idx = (size_t)row * HID + c0 + tx;
    float v = bf2f(P[idx]);
#pragma unroll 1
    for (int zz = 1; zz < nz; ++zz) v += bf2f(P[(size_t)zz * MN + idx]);
    v += bias[c0 + tx];
    v = fmaxf(v, 0.0f);
    xn[(size_t)row * HID + colp] = (short)f2bf(v);
    t[ty + 8 * i][tx] = v;
  }
  __syncthreads();
  int ip = pos32(pos32(tx));   // inverse perm
#pragma unroll
  for (int i = 0; i < 4; ++i) {
    int cl = ty + 8 * i;
    xnT[(size_t)(c0 + cl) * N_NODES + r0 + tx] = (short)f2bf(t[ip][cl]);
  }
}

// ---------------------------------------------------------------------------
// Head part 1 (bf16 x2 input, plain layout): per-row scores/rowsum
// (blocks [0,2048), one s16x8 per thread covers the row) and per-col
// partial sums for pooled ([2048,2304)).
// ---------------------------------------------------------------------------
__global__ __launch_bounds__(256) void scores_pooled_kernel(
    const short* __restrict__ x2b, const float* __restrict__ Wa,
    const float* __restrict__ ba, float* __restrict__ scores,
    float* __restrict__ rowsum, float* __restrict__ partial)
{
  int bid = blockIdx.x, tid = threadIdx.x;
  if (bid < N_NODES) {
    const short* row = x2b + (size_t)bid * HID;
    int f0 = tid * 8;                    // 256 threads x 8 = 2048 = HID
    s16x8 u = *reinterpret_cast<const s16x8*>(&row[f0]);
    float s = 0.0f, r = 0.0f;
#pragma unroll
    for (int j = 0; j < 8; ++j) {
      float v = bf2f(u[j]);
      s = fmaf(v, Wa[f0 + j], s);
      r += v;
    }
#pragma unroll
    for (int off = 32; off; off >>= 1) {
      s += __shfl_down(s, off);
      r += __shfl_down(r, off);
    }
    __shared__ float sred[4], rred[4];
    if ((tid & 63) == 0) { sred[tid >> 6] = s; rred[tid >> 6] = r; }
    __syncthreads();
    if (tid == 0) {
      scores[bid] = sred[0] + sred[1] + sred[2] + sred[3] + ba[0];
      rowsum[bid] = rred[0] + rred[1] + rred[2] + rred[3];
    }
  } else {
    int q = bid - N_NODES;              // 0..255
    int f  = (q & 7) * 256 + tid;
    int r0 = (q >> 3) * 64;
    float s = 0.0f;
#pragma unroll 4
    for (int r = 0; r < 64; ++r) s += bf2f(x2b[(size_t)(r0 + r) * HID + f]);
    partial[(size_t)(q >> 3) * HID + f] = s;
  }
}

// ---------------------------------------------------------------------------
// Head part 2 (single block, 1024 threads): softmax over scores -> ge (LDS),
// pooled from partial (LDS), final linear -> out[16].
// ---------------------------------------------------------------------------
__global__ __launch_bounds__(1024) void tail_kernel(
    const float* __restrict__ scores, const float* __restrict__ rowsum,
    const float* __restrict__ partial,
    const float* __restrict__ Wf, const float* __restrict__ bf,
    float* __restrict__ out)
{
  __shared__ float ge_s[N_NODES];
  __shared__ float pl[HID];
  __shared__ float part[64][NCLS];
  __shared__ float red[16];
  __shared__ float Msh, Zsh;
  int tid = threadIdx.x;

  float m = -1e30f;
  for (int n = tid; n < N_NODES; n += 1024) m = fmaxf(m, scores[n]);
#pragma unroll
  for (int off = 32; off; off >>= 1) m = fmaxf(m, __shfl_down(m, off));
  if ((tid & 63) == 0) red[tid >> 6] = m;
  __syncthreads();
  if (tid == 0) {
    float mm = red[0];
#pragma unroll
    for (int k = 1; k < 16; ++k) mm = fmaxf(mm, red[k]);
    Msh = mm;
  }
  __syncthreads();
  float M = Msh;

  float z = 0.0f;
  for (int n = tid; n < N_NODES; n += 1024) z += expf(scores[n] - M);
#pragma unroll
  for (int off = 32; off; off >>= 1) z += __shfl_down(z, off);
  __syncthreads();
  if ((tid & 63) == 0) red[tid >> 6] = z;
  __syncthreads();
  if (tid == 0) {
    float zz = 0.0f;
#pragma unroll
    for (int k = 0; k < 16; ++k) zz += red[k];
    Zsh = zz;
  }
  __syncthreads();
  float Z = Zsh;

  for (int n = tid; n < N_NODES; n += 1024)
    ge_s[n] = expf(scores[n] - M) / Z * rowsum[n];

  for (int f = tid; f < HID; f += 1024) {
    float s = 0.0f;
#pragma unroll
    for (int r = 0; r < 32; ++r) s += partial[(size_t)r * HID + f];
    pl[f] = s * (1.0f / N_NODES);
  }
  __syncthreads();

  int c = tid & 15, gg = tid >> 4;      // 64 groups of 16 classes
  float s = 0.0f;
  for (int j = gg; j < HID; j += 64) {
    s = fmaf(pl[j],   Wf[(size_t)j * NCLS + c], s);
    s = fmaf(ge_s[j], Wf[(size_t)(HID + j) * NCLS + c], s);
  }
  part[gg][c] = s;
  __syncthreads();
  if (tid < NCLS) {
    float tsum = 0.0f;
#pragma unroll
    for (int k = 0; k < 64; ++k) tsum += part[k][tid];
    out[tid] = tsum + bf[tid];
  }
}

// ---------------------------------------------------------------------------
extern "C" void kernel_launch(void* const* d_in, const int* in_sizes, int n_in,
                              void* d_out, int out_size, void* d_ws, size_t ws_size,
                              hipStream_t stream) {
  const float* x   = (const float*)d_in[0];
  const int*   src = (const int*)  d_in[1];
  const int*   dst = (const int*)  d_in[2];
  const float* W1l = (const float*)d_in[3];
  const float* b1  = (const float*)d_in[4];
  const float* W1r = (const float*)d_in[5];
  const float* W2l = (const float*)d_in[6];
  const float* b2  = (const float*)d_in[7];
  const float* W2r = (const float*)d_in[8];
  const float* Wa  = (const float*)d_in[9];
  const float* ba  = (const float*)d_in[10];
  const float* Wf  = (const float*)d_in[11];
  const float* bf  = (const float*)d_in[12];
  float* out = (float*)d_out;

  const size_t MB = 1u << 20;
  char* w = (char*)d_ws;
  // Lifetime-overlaid layout (~99 MB peak):
  short* P      = (short*)(w);              // 0-32MB: bf16 partials (<=16 slices)
  float* adjf   = (float*)(w + 32 * MB);    // 32-48MB; dead after prep
  short* x2b    = (short*)(w + 32 * MB);    //   overlay (written by x2-combine)
  float* rsums  = (float*)(w + 48 * MB);    // 8KB, contiguous after adjf
  short* adjb   = (short*)(w + 56 * MB);    // 56-64; dead after mean2
  short* meanb2 = (short*)(w + 56 * MB);    //   overlay (written after mean2)
  short* W2lT   = (short*)(w + 64 * MB);    // 64-72
  short* W2rT   = (short*)(w + 72 * MB);    // 72-80
  short* x1b    = (short*)(w + 80 * MB);    // 80-88
  short* xb     = (short*)(w + 88 * MB);    // 88-90; dead after x1 gemm
  short* xT     = (short*)(w + 90 * MB);    // 90-92
  short* W1lT   = (short*)(w + 92 * MB);    // 92-94
  short* W1rT   = (short*)(w + 94 * MB);    // 94-96
  short* x1T    = (short*)(w + 88 * MB);    //   overlay 88-96 (after x1 gemm)
  short* meanb  = (short*)(w + 96 * MB);    // 96-98; dead after x1 gemm
  float* scores = (float*)(w + 98 * MB);
  float* rowsum = scores + N_NODES;
  float* partial= rowsum + N_NODES;         // 32*2048

  // one memset covers adjf (16MB) + rsums (8KB) contiguously
  hipMemsetAsync(adjf, 0, (size_t)N_NODES * N_NODES * sizeof(float)
                          + N_NODES * sizeof(float), stream);

  build_adj_kernel<<<E_EDGES / 256, 256, 0, stream>>>(src, dst, adjf);

  prep_kernel<<<16384, 256, 0, stream>>>(adjf, adjb, rsums, x, xb, xT,
                                         W1l, W1lT, W1r, W1rT,
                                         W2l, W2lT, W2r, W2rT);

  // mean1 = rowscale(adj @ x): grid 2x8x16 decode, nz=16 (4 K-tiles/block)
  gemm256<<<256, 512, 0, stream>>>(
      adjb, xT, N_NODES, nullptr, nullptr, 0, 16, 2, P, N_NODES, IN_DIM);
  combine_kernel<<<(N_NODES * IN_DIM / 4) / 256, 256, 0, stream>>>(
      P, 16, (size_t)N_NODES * IN_DIM, rsums, 9, nullptr, 0, 0, meanb, 1, nullptr);

  // x1 = relu(mean1 @ W1l + x @ W1r + b1): pair-fused, nz=4 (8 K-tiles)
  gemm256<<<256, 512, 0, stream>>>(
      meanb, W1lT, IN_DIM, xb, W1rT, IN_DIM, 4, 8, P, N_NODES, HID);
  combine_tr_kernel<<<dim3(HID / 32, N_NODES / 32), 256, 0, stream>>>(
      P, 4, b1, x1b, x1T);

  // mean2 = rowscale(adj @ x1): nz=4 (16 K-tiles)
  gemm256<<<256, 512, 0, stream>>>(
      adjb, x1T, N_NODES, nullptr, nullptr, 0, 4, 8, P, N_NODES, HID);
  combine_kernel<<<(N_NODES * HID / 4) / 256, 256, 0, stream>>>(
      P, 4, (size_t)N_NODES * HID, rsums, 11, nullptr, 0, 0, meanb2, 1, nullptr);

  // x2 = relu(mean2 @ W2l + x1 @ W2r + b2): pair-fused, nz=4 (32 K-tiles)
  gemm256<<<256, 512, 0, stream>>>(
      meanb2, W2lT, HID, x1b, W2rT, HID, 4, 8, P, N_NODES, HID);
  combine_kernel<<<(N_NODES * HID / 4) / 256, 256, 0, stream>>>(
      P, 4, (size_t)N_NODES * HID, nullptr, 0, b2, HID - 1, 1, x2b, 0, nullptr);

  // head (bf16 x2)
  scores_pooled_kernel<<<N_NODES + 256, 256, 0, stream>>>(x2b, Wa, ba, scores, rowsum, partial);
  tail_kernel<<<1, 1024, 0, stream>>>(scores, rowsum, partial, Wf, bf, out);
}

// Round 16
// 197.416 us; speedup vs baseline: 1.0590x; 1.0590x over previous
//
#include <hip/hip_runtime.h>
#include <hip/hip_bf16.h>
#include <cstddef>
#include <cstdint>

#define N_NODES 2048
#define E_EDGES 131072
#define IN_DIM  512
#define HID     2048
#define NCLS    16

typedef __bf16 bf16x8 __attribute__((ext_vector_type(8)));
typedef short  s16x4  __attribute__((ext_vector_type(4)));
typedef short  s16x8  __attribute__((ext_vector_type(8)));
typedef float  f32x4  __attribute__((ext_vector_type(4)));

__device__ __forceinline__ unsigned short f2bf(float f) {
  unsigned u = __builtin_bit_cast(unsigned, f);
  u = (u + 0x7FFFu + ((u >> 16) & 1u)) >> 16;
  return (unsigned short)u;
}
__device__ __forceinline__ float bf2f(short h) {
  unsigned u = (unsigned)(unsigned short)h << 16;
  return __builtin_bit_cast(float, u);
}

// K-permutation within each 32-col block: lane g's 8-elem MFMA fragment
// (k = g*4+{0..3}, g*4+16+{0..3}) becomes contiguous slots [8g,8g+8) -> one
// ds_read_b128 per fragment. pos32 is a bit 3-cycle; inverse = pos32 twice.
__device__ __forceinline__ int pos32(int k) {
  return (((k >> 2) & 3) << 3) | (((k >> 4) & 1) << 2) | (k & 3);
}

#define GLD16(gp, lp) __builtin_amdgcn_global_load_lds(                     \
    (__attribute__((address_space(1))) void*)(gp),                          \
    (__attribute__((address_space(3))) void*)(lp), 16, 0, 0)

#define WAITVM(N) asm volatile("s_waitcnt vmcnt(" #N ")" ::: "memory")
#define WAITLGKM0() do { asm volatile("s_waitcnt lgkmcnt(0)" ::: "memory"); \
                         __builtin_amdgcn_sched_barrier(0); } while (0)

// ---------------------------------------------------------------------------
// Dense adjacency build; columns stored K-PERMUTED (perm folded into atomics).
// ---------------------------------------------------------------------------
__global__ void build_adj_kernel(const int* __restrict__ src, const int* __restrict__ dst,
                                 float* __restrict__ adj) {
  int e = blockIdx.x * blockDim.x + threadIdx.x;
  if (e < E_EDGES) {
    int s = src[e], d = dst[e];
    int sp = (s & ~31) | pos32(s & 31);
    atomicAdd(&adj[(size_t)d * N_NODES + sp], 1.0f);
  }
}

// ---------------------------------------------------------------------------
// Fused operand prep; adj-cvt blocks also accumulate per-row degree sums
// (exact integer fp32 partials, commutative -> deterministic).
// ---------------------------------------------------------------------------
__global__ __launch_bounds__(256) void prep_kernel(
    const float* __restrict__ adjf, short* __restrict__ adjb,
    float* __restrict__ rsums,
    const float* __restrict__ x,   short* __restrict__ xb,   short* __restrict__ xT,
    const float* __restrict__ W1l, short* __restrict__ W1lT,
    const float* __restrict__ W1r, short* __restrict__ W1rT,
    const float* __restrict__ W2l, short* __restrict__ W2lT,
    const float* __restrict__ W2r, short* __restrict__ W2rT)
{
  int bid = blockIdx.x, tid = threadIdx.x;
  if (bid < 4096) {                         // adj cvt (plain layout) + row sums
    size_t flat = ((size_t)bid * 256 + tid) * 4;
    float4 v = *reinterpret_cast<const float4*>(&adjf[flat]);
    s16x4 o;
    o[0] = (short)f2bf(v.x); o[1] = (short)f2bf(v.y);
    o[2] = (short)f2bf(v.z); o[3] = (short)f2bf(v.w);
    *reinterpret_cast<s16x4*>(&adjb[flat]) = o;
    float ls = v.x + v.y + v.z + v.w;       // counts: exact in fp32
#pragma unroll
    for (int off = 32; off; off >>= 1) ls += __shfl_down(ls, off);
    __shared__ float wred[4];
    if ((tid & 63) == 0) wred[tid >> 6] = ls;
    __syncthreads();
    if (tid == 0)
      atomicAdd(&rsums[bid >> 1], wred[0] + wred[1] + wred[2] + wred[3]);
    return;
  }
  bid -= 4096;
  if (bid < 1024) {                         // x cvt, perm slots
    size_t flat = ((size_t)bid * 256 + tid) * 4;
    float4 v = *reinterpret_cast<const float4*>(&x[flat]);
    s16x4 o;
    o[0] = (short)f2bf(v.x); o[1] = (short)f2bf(v.y);
    o[2] = (short)f2bf(v.z); o[3] = (short)f2bf(v.w);
    size_t base = (flat & ~(size_t)31) | (size_t)pos32((int)(flat & 31));
    *reinterpret_cast<s16x4*>(&xb[base]) = o;
    return;
  }
  bid -= 1024;
  __shared__ float t[32][33];
  const float* in; short* outp; int R, C, bx, by;
  if (bid < 1024)      { in = x;   outp = xT;   R = N_NODES; C = IN_DIM; bx = bid & 15; by = bid >> 4; }
  else if (bid < 2048) { bid -= 1024; in = W1l; outp = W1lT; R = IN_DIM; C = HID; bx = bid & 63; by = bid >> 6; }
  else if (bid < 3072) { bid -= 2048; in = W1r; outp = W1rT; R = IN_DIM; C = HID; bx = bid & 63; by = bid >> 6; }
  else if (bid < 7168) { bid -= 3072; in = W2l; outp = W2lT; R = HID;    C = HID; bx = bid & 63; by = bid >> 6; }
  else                 { bid -= 7168; in = W2r; outp = W2rT; R = HID;    C = HID; bx = bid & 63; by = bid >> 6; }
  int c0 = bx * 32, r0 = by * 32;
  int tx = tid & 31, ty = tid >> 5;
#pragma unroll
  for (int i = 0; i < 4; ++i)
    t[ty + 8 * i][tx] = in[(size_t)(r0 + ty + 8 * i) * C + c0 + tx];
  __syncthreads();
  int ip = pos32(pos32(tx));   // inverse perm
#pragma unroll
  for (int i = 0; i < 4; ++i)
    outp[(size_t)(c0 + ty + 8 * i) * R + r0 + tx] = (short)f2bf(t[ip][ty + 8 * i]);
}

// ---------------------------------------------------------------------------
// 256x256 bf16 MFMA GEMM (R12's verified pipeline) + COALESCED LDS EPILOGUE.
// 512 threads = 8 waves (2M x 4N), wave-tile 128x64, BK=32; 4-buffer LDS,
// counted vmcnt(8), phased schedule, XCD-aware 1D decode, bf16 partials.
// Epilogue: after the K-loop the 128 KB LDS (exactly one 256x256 bf16
// C-tile) is dead; stage all 8 32-row slabs, bank-swizzled, then read b128
// row-major and store 16B/lane: full-line writes.
// Ledger: prologue tiles 0-2; iter t: WAITVM(8)->tile t resident; buffer
// (t+3)&3 last read iter t-1 (barrier-separated); tails vm4/vm0.
// ---------------------------------------------------------------------------
__global__ __launch_bounds__(512) void gemm256(
    const short* __restrict__ A1, const short* __restrict__ B1, int K1,
    const short* __restrict__ A2, const short* __restrict__ B2, int K2,
    int nz, int gx, short* __restrict__ P, int M, int N)
{
  __shared__ short As[4][256 * 32];   // 4 x 16 KB
  __shared__ short Bs[4][256 * 32];   // 4 x 16 KB  (128 KB total)

  const int tid = threadIdx.x, wid = tid >> 6, lane = tid & 63;
  const int g = lane >> 4, r16 = lane & 15;
  const int wm = (wid >> 2) * 128, wn = (wid & 3) * 64;

  // XCD-aware decode (HW maps block L -> XCD L%8)
  const int L = blockIdx.x;
  const int xcd = L & 7, w = L >> 3;
  int bnI, byI, z;
  if (gx == 8) { z = xcd >> 1; bnI = w & 7; byI = ((xcd & 1) << 2) + (w >> 3); }
  else         { bnI = (w >> 1) & 1; byI = w >> 2; z = xcd * 2 + (w & 1); }
  const int bm = byI * 256, bn = bnI * 256;

  const int s1  = K1 / nz / 32;
  const int s2  = A2 ? K2 / nz / 32 : 0;
  const int k01 = z * (K1 / nz);
  const int k02 = A2 ? z * (K2 / nz) : 0;
  const int total = s1 + s2;
  short* Pz = P + (size_t)z * M * N;

  auto SRC = [&](int t, const short*& A, const short*& B, int& lda, int& k) {
    if (t < s1) { A = A1; B = B1; lda = K1; k = k01 + t * 32; }
    else        { A = A2; B = B2; lda = K2; k = k02 + (t - s1) * 32; }
  };
  auto STAGE_A = [&](int t) {
    const short* A; const short* B; int lda, k;
    SRC(t, A, B, lda, k);
    int buf = t & 3;
#pragma unroll
    for (int h = 0; h < 2; ++h) {
      int Pl = h * 512 + tid;               // 0..1023 (16B units)
      int m = Pl >> 2, U = Pl & 3;
      int v = U ^ ((m >> 1) & 3);
      GLD16(A + (size_t)(bm + m) * lda + k + v * 8, &As[buf][(h * 512 + wid * 64) * 8]);
    }
  };
  auto STAGE_B = [&](int t) {
    const short* A; const short* B; int lda, k;
    SRC(t, A, B, lda, k);
    int buf = t & 3;
#pragma unroll
    for (int h = 0; h < 2; ++h) {
      int Pl = h * 512 + tid;
      int n = Pl >> 2, U = Pl & 3;
      int v = U ^ ((n >> 1) & 3);
      GLD16(B + (size_t)(bn + n) * lda + k + v * 8, &Bs[buf][(h * 512 + wid * 64) * 8]);
    }
  };

  f32x4 acc[8][4];
#pragma unroll
  for (int mi = 0; mi < 8; ++mi)
#pragma unroll
    for (int ni = 0; ni < 4; ++ni)
#pragma unroll
      for (int r = 0; r < 4; ++r) acc[mi][ni][r] = 0.0f;

  bf16x8 bfr[4];
  auto READ_B = [&](int buf) {
#pragma unroll
    for (int ni = 0; ni < 4; ++ni) {
      int n = wn + ni * 16 + r16;
      bfr[ni] = __builtin_bit_cast(bf16x8, *(const s16x8*)&Bs[buf][n * 32 + ((g ^ ((n >> 1) & 3)) << 3)]);
    }
  };
  bf16x8 afr[4];
  auto READ_A = [&](int buf, int mlo) {
#pragma unroll
    for (int i = 0; i < 4; ++i) {
      int m = wm + (mlo + i) * 16 + r16;
      afr[i] = __builtin_bit_cast(bf16x8, *(const s16x8*)&As[buf][m * 32 + ((g ^ ((m >> 1) & 3)) << 3)]);
    }
  };
  auto MMA = [&](int mlo) {
    __builtin_amdgcn_s_setprio(1);
#pragma unroll
    for (int i = 0; i < 4; ++i)
#pragma unroll
      for (int ni = 0; ni < 4; ++ni)
        acc[mlo + i][ni] = __builtin_amdgcn_mfma_f32_16x16x32_bf16(afr[i], bfr[ni], acc[mlo + i][ni], 0, 0, 0);
    __builtin_amdgcn_s_setprio(0);
  };

  // prologue: tiles 0..2, issue order A,B per tile (vmcnt FIFO = this order)
  STAGE_A(0); STAGE_B(0);
  STAGE_A(1); STAGE_B(1);
  STAGE_A(2); STAGE_B(2);

#pragma unroll 1
  for (int t = 0; t < total - 2; ++t) {
    const int buf = t & 3;
    WAITVM(8);
    __builtin_amdgcn_s_barrier();       // tile t resident for all waves
    __builtin_amdgcn_sched_barrier(0);
    // ---- phase 0 ----
    READ_B(buf); READ_A(buf, 0);
    if (t + 3 < total) STAGE_A(t + 3);
    __builtin_amdgcn_sched_barrier(0);
    __builtin_amdgcn_s_barrier();
    WAITLGKM0();
    MMA(0);
    // ---- phase 1 ----
    READ_A(buf, 4);
    if (t + 3 < total) STAGE_B(t + 3);
    __builtin_amdgcn_sched_barrier(0);
    __builtin_amdgcn_s_barrier();
    WAITLGKM0();
    MMA(4);
  }
  {
    const int buf = (total - 2) & 3;
    WAITVM(4);
    __builtin_amdgcn_s_barrier();
    __builtin_amdgcn_sched_barrier(0);
    READ_B(buf); READ_A(buf, 0);
    __builtin_amdgcn_s_barrier();
    WAITLGKM0();
    MMA(0);
    READ_A(buf, 4);
    __builtin_amdgcn_s_barrier();
    WAITLGKM0();
    MMA(4);
  }
  {
    const int buf = (total - 1) & 3;
    WAITVM(0);
    __builtin_amdgcn_s_barrier();
    __builtin_amdgcn_sched_barrier(0);
    READ_B(buf); READ_A(buf, 0);
    WAITLGKM0();
    MMA(0);
    READ_A(buf, 4);
    WAITLGKM0();
    MMA(4);
  }

  // ---- coalesced epilogue: stage full C-tile in LDS, store full lines ----
  __builtin_amdgcn_s_barrier();         // all waves done with LDS tile reads
  {
    const int rlb = (wid >> 2) * 16 + g * 4;      // slab-local row base
#pragma unroll
    for (int mi = 0; mi < 8; ++mi) {
      short* slabp = (mi < 4) ? &As[mi][0] : &Bs[mi - 4][0];
#pragma unroll
      for (int ni = 0; ni < 4; ++ni) {
        int c = wn + ni * 16 + r16;
#pragma unroll
        for (int r = 0; r < 4; ++r) {
          int rr = rlb + r;                       // 0..31
          int cp = c ^ (((rr >> 2) & 3) << 4);    // bank swizzle
          slabp[rr * 256 + cp] = (short)f2bf(acc[mi][ni][r]);
        }
      }
    }
  }
  __builtin_amdgcn_s_barrier();
  {
    const int rr = tid >> 4;                      // 0..31
    const int growbase = bm + ((rr & 16) << 3) + (rr & 15);
    const int sw = ((rr >> 2) & 3) << 4;
#pragma unroll
    for (int mi = 0; mi < 8; ++mi) {
      const short* slabp = (mi < 4) ? &As[mi][0] : &Bs[mi - 4][0];
      size_t rowoff = (size_t)(growbase + mi * 16) * N + bn;
#pragma unroll
      for (int p = 0; p < 2; ++p) {
        int cbase = ((tid & 15) + p * 16) * 8;    // logical col, 8-aligned
        s16x8 v = *(const s16x8*)&slabp[rr * 256 + (cbase ^ sw)];
        *reinterpret_cast<s16x8*>(&Pz[rowoff + cbase]) = v;
      }
    }
  }
}

// ---------------------------------------------------------------------------
// Combine bf16 z-partials: sum, optional 1/max(rsums[row],1) scale, bias,
// relu; write fp32 plain and/or bf16 (K-permuted if permB, else plain).
// ---------------------------------------------------------------------------
__global__ __launch_bounds__(256) void combine_kernel(
    const short* P, int nz, size_t MN,
    const float* rsums, int rshift,
    const float* bias, int cmask, int doRelu,
    short* outb, int permB, float* outf)
{
  size_t flat = ((size_t)blockIdx.x * 256 + threadIdx.x) * 4;
  if (flat >= MN) return;
  s16x4 t4 = *reinterpret_cast<const s16x4*>(&P[flat]);
  float4 s = make_float4(bf2f(t4[0]), bf2f(t4[1]), bf2f(t4[2]), bf2f(t4[3]));
#pragma unroll 1
  for (int zz = 1; zz < nz; ++zz) {
    s16x4 u4 = *reinterpret_cast<const s16x4*>(&P[(size_t)zz * MN + flat]);
    s.x += bf2f(u4[0]); s.y += bf2f(u4[1]); s.z += bf2f(u4[2]); s.w += bf2f(u4[3]);
  }
  if (rsums) {
    float sc = 1.0f / fmaxf(rsums[flat >> rshift], 1.0f);
    s.x *= sc; s.y *= sc; s.z *= sc; s.w *= sc;
  }
  if (bias) {
    float4 bv = *reinterpret_cast<const float4*>(&bias[flat & (size_t)cmask]);
    s.x += bv.x; s.y += bv.y; s.z += bv.z; s.w += bv.w;
  }
  if (doRelu) {
    s.x = fmaxf(s.x, 0.0f); s.y = fmaxf(s.y, 0.0f);
    s.z = fmaxf(s.z, 0.0f); s.w = fmaxf(s.w, 0.0f);
  }
  if (outf) *reinterpret_cast<float4*>(&outf[flat]) = s;
  if (outb) {
    s16x4 o;
    o[0] = (short)f2bf(s.x); o[1] = (short)f2bf(s.y);
    o[2] = (short)f2bf(s.z); o[3] = (short)f2bf(s.w);
    size_t base = permB ? ((flat & ~(size_t)31) | (size_t)pos32((int)(flat & 31)))
                        : flat;
    *reinterpret_cast<s16x4*>(&outb[base]) = o;
  }
}

// ---------------------------------------------------------------------------
// x1 finisher: sum nz bf16 partials + bias + relu, write x1b (bf16, perm
// cols) AND x1T (bf16, transposed, perm slots). Grid (HID/32, N/32).
// ---------------------------------------------------------------------------
__global__ __launch_bounds__(256) void combine_tr_kernel(
    const short* __restrict__ P, int nz,
    const float* __restrict__ bias,
    short* __restrict__ xn, short* __restrict__ xnT)
{
  __shared__ float t[32][33];
  const size_t MN = (size_t)N_NODES * HID;
  int c0 = blockIdx.x * 32, r0 = blockIdx.y * 32;
  int tx = threadIdx.x & 31, ty = threadIdx.x >> 5;
  int colp = c0 + pos32(tx);
#pragma unroll
  for (int i = 0; i < 4; ++i) {
    int row = r0 + ty + 8 * i;
    size_t idx = (size_t)row * HID + c0 + tx;
    float v = bf2f(P[idx]);
#pragma unroll 1
    for (int zz = 1; zz < nz; ++zz) v += bf2f(P[(size_t)zz * MN + idx]);
    v += bias[c0 + tx];
    v = fmaxf(v, 0.0f);
    xn[(size_t)row * HID + colp] = (short)f2bf(v);
    t[ty + 8 * i][tx] = v;
  }
  __syncthreads();
  int ip = pos32(pos32(tx));   // inverse perm
#pragma unroll
  for (int i = 0; i < 4; ++i) {
    int cl = ty + 8 * i;
    xnT[(size_t)(c0 + cl) * N_NODES + r0 + tx] = (short)f2bf(t[ip][cl]);
  }
}

// ---------------------------------------------------------------------------
// Head part 1 (bf16 x2 input, plain layout): per-row scores/rowsum
// (blocks [0,2048), one s16x8 per thread covers the row) and per-col
// partial sums for pooled ([2048,2304)).
// ---------------------------------------------------------------------------
__global__ __launch_bounds__(256) void scores_pooled_kernel(
    const short* __restrict__ x2b, const float* __restrict__ Wa,
    const float* __restrict__ ba, float* __restrict__ scores,
    float* __restrict__ rowsum, float* __restrict__ partial)
{
  int bid = blockIdx.x, tid = threadIdx.x;
  if (bid < N_NODES) {
    const short* row = x2b + (size_t)bid * HID;
    int f0 = tid * 8;                    // 256 threads x 8 = 2048 = HID
    s16x8 u = *reinterpret_cast<const s16x8*>(&row[f0]);
    float s = 0.0f, r = 0.0f;
#pragma unroll
    for (int j = 0; j < 8; ++j) {
      float v = bf2f(u[j]);
      s = fmaf(v, Wa[f0 + j], s);
      r += v;
    }
#pragma unroll
    for (int off = 32; off; off >>= 1) {
      s += __shfl_down(s, off);
      r += __shfl_down(r, off);
    }
    __shared__ float sred[4], rred[4];
    if ((tid & 63) == 0) { sred[tid >> 6] = s; rred[tid >> 6] = r; }
    __syncthreads();
    if (tid == 0) {
      scores[bid] = sred[0] + sred[1] + sred[2] + sred[3] + ba[0];
      rowsum[bid] = rred[0] + rred[1] + rred[2] + rred[3];
    }
  } else {
    int q = bid - N_NODES;              // 0..255
    int f  = (q & 7) * 256 + tid;
    int r0 = (q >> 3) * 64;
    float s = 0.0f;
#pragma unroll 4
    for (int r = 0; r < 64; ++r) s += bf2f(x2b[(size_t)(r0 + r) * HID + f]);
    partial[(size_t)(q >> 3) * HID + f] = s;
  }
}

// ---------------------------------------------------------------------------
// Head part 2 (single block, 1024 threads): softmax over scores -> ge (LDS),
// pooled from partial (LDS), final linear -> out[16].
// ---------------------------------------------------------------------------
__global__ __launch_bounds__(1024) void tail_kernel(
    const float* __restrict__ scores, const float* __restrict__ rowsum,
    const float* __restrict__ partial,
    const float* __restrict__ Wf, const float* __restrict__ bf,
    float* __restrict__ out)
{
  __shared__ float ge_s[N_NODES];
  __shared__ float pl[HID];
  __shared__ float part[64][NCLS];
  __shared__ float red[16];
  __shared__ float Msh, Zsh;
  int tid = threadIdx.x;

  float m = -1e30f;
  for (int n = tid; n < N_NODES; n += 1024) m = fmaxf(m, scores[n]);
#pragma unroll
  for (int off = 32; off; off >>= 1) m = fmaxf(m, __shfl_down(m, off));
  if ((tid & 63) == 0) red[tid >> 6] = m;
  __syncthreads();
  if (tid == 0) {
    float mm = red[0];
#pragma unroll
    for (int k = 1; k < 16; ++k) mm = fmaxf(mm, red[k]);
    Msh = mm;
  }
  __syncthreads();
  float M = Msh;

  float z = 0.0f;
  for (int n = tid; n < N_NODES; n += 1024) z += expf(scores[n] - M);
#pragma unroll
  for (int off = 32; off; off >>= 1) z += __shfl_down(z, off);
  __syncthreads();
  if ((tid & 63) == 0) red[tid >> 6] = z;
  __syncthreads();
  if (tid == 0) {
    float zz = 0.0f;
#pragma unroll
    for (int k = 0; k < 16; ++k) zz += red[k];
    Zsh = zz;
  }
  __syncthreads();
  float Z = Zsh;

  for (int n = tid; n < N_NODES; n += 1024)
    ge_s[n] = expf(scores[n] - M) / Z * rowsum[n];

  for (int f = tid; f < HID; f += 1024) {
    float s = 0.0f;
#pragma unroll
    for (int r = 0; r < 32; ++r) s += partial[(size_t)r * HID + f];
    pl[f] = s * (1.0f / N_NODES);
  }
  __syncthreads();

  int c = tid & 15, gg = tid >> 4;      // 64 groups of 16 classes
  float s = 0.0f;
  for (int j = gg; j < HID; j += 64) {
    s = fmaf(pl[j],   Wf[(size_t)j * NCLS + c], s);
    s = fmaf(ge_s[j], Wf[(size_t)(HID + j) * NCLS + c], s);
  }
  part[gg][c] = s;
  __syncthreads();
  if (tid < NCLS) {
    float tsum = 0.0f;
#pragma unroll
    for (int k = 0; k < 64; ++k) tsum += part[k][tid];
    out[tid] = tsum + bf[tid];
  }
}

// ---------------------------------------------------------------------------
extern "C" void kernel_launch(void* const* d_in, const int* in_sizes, int n_in,
                              void* d_out, int out_size, void* d_ws, size_t ws_size,
                              hipStream_t stream) {
  const float* x   = (const float*)d_in[0];
  const int*   src = (const int*)  d_in[1];
  const int*   dst = (const int*)  d_in[2];
  const float* W1l = (const float*)d_in[3];
  const float* b1  = (const float*)d_in[4];
  const float* W1r = (const float*)d_in[5];
  const float* W2l = (const float*)d_in[6];
  const float* b2  = (const float*)d_in[7];
  const float* W2r = (const float*)d_in[8];
  const float* Wa  = (const float*)d_in[9];
  const float* ba  = (const float*)d_in[10];
  const float* Wf  = (const float*)d_in[11];
  const float* bf  = (const float*)d_in[12];
  float* out = (float*)d_out;

  const size_t MB = 1u << 20;
  char* w = (char*)d_ws;
  // Lifetime-overlaid layout (~99 MB peak):
  short* P      = (short*)(w);              // 0-32MB: bf16 partials (<=16 slices)
  float* adjf   = (float*)(w + 32 * MB);    // 32-48MB; dead after prep
  short* x2b    = (short*)(w + 32 * MB);    //   overlay (written by x2-combine)
  float* rsums  = (float*)(w + 48 * MB);    // 8KB, contiguous after adjf
  short* adjb   = (short*)(w + 56 * MB);    // 56-64; dead after mean2
  short* meanb2 = (short*)(w + 56 * MB);    //   overlay (written after mean2)
  short* W2lT   = (short*)(w + 64 * MB);    // 64-72
  short* W2rT   = (short*)(w + 72 * MB);    // 72-80
  short* x1b    = (short*)(w + 80 * MB);    // 80-88
  short* xb     = (short*)(w + 88 * MB);    // 88-90; dead after x1 gemm
  short* xT     = (short*)(w + 90 * MB);    // 90-92
  short* W1lT   = (short*)(w + 92 * MB);    // 92-94
  short* W1rT   = (short*)(w + 94 * MB);    // 94-96
  short* x1T    = (short*)(w + 88 * MB);    //   overlay 88-96 (after x1 gemm)
  short* meanb  = (short*)(w + 96 * MB);    // 96-98; dead after x1 gemm
  float* scores = (float*)(w + 98 * MB);
  float* rowsum = scores + N_NODES;
  float* partial= rowsum + N_NODES;         // 32*2048

  // one memset covers adjf (16MB) + rsums (8KB) contiguously
  hipMemsetAsync(adjf, 0, (size_t)N_NODES * N_NODES * sizeof(float)
                          + N_NODES * sizeof(float), stream);

  build_adj_kernel<<<E_EDGES / 256, 256, 0, stream>>>(src, dst, adjf);

  prep_kernel<<<16384, 256, 0, stream>>>(adjf, adjb, rsums, x, xb, xT,
                                         W1l, W1lT, W1r, W1rT,
                                         W2l, W2lT, W2r, W2rT);

  // mean1 = rowscale(adj @ x): grid 2x8x16 decode, nz=16 (4 K-tiles/block)
  gemm256<<<256, 512, 0, stream>>>(
      adjb, xT, N_NODES, nullptr, nullptr, 0, 16, 2, P, N_NODES, IN_DIM);
  combine_kernel<<<(N_NODES * IN_DIM / 4) / 256, 256, 0, stream>>>(
      P, 16, (size_t)N_NODES * IN_DIM, rsums, 9, nullptr, 0, 0, meanb, 1, nullptr);

  // x1 = relu(mean1 @ W1l + x @ W1r + b1): pair-fused, nz=4 (8 K-tiles)
  gemm256<<<256, 512, 0, stream>>>(
      meanb, W1lT, IN_DIM, xb, W1rT, IN_DIM, 4, 8, P, N_NODES, HID);
  combine_tr_kernel<<<dim3(HID / 32, N_NODES / 32), 256, 0, stream>>>(
      P, 4, b1, x1b, x1T);

  // mean2 = rowscale(adj @ x1): nz=4 (16 K-tiles)
  gemm256<<<256, 512, 0, stream>>>(
      adjb, x1T, N_NODES, nullptr, nullptr, 0, 4, 8, P, N_NODES, HID);
  combine_kernel<<<(N_NODES * HID / 4) / 256, 256, 0, stream>>>(
      P, 4, (size_t)N_NODES * HID, rsums, 11, nullptr, 0, 0, meanb2, 1, nullptr);

  // x2 = relu(mean2 @ W2l + x1 @ W2r + b2): pair-fused, nz=4 (32 K-tiles)
  gemm256<<<256, 512, 0, stream>>>(
      meanb2, W2lT, HID, x1b, W2rT, HID, 4, 8, P, N_NODES, HID);
  combine_kernel<<<(N_NODES * HID / 4) / 256, 256, 0, stream>>>(
      P, 4, (size_t)N_NODES * HID, nullptr, 0, b2, HID - 1, 1, x2b, 0, nullptr);

  // head (bf16 x2)
  scores_pooled_kernel<<<N_NODES + 256, 256, 0, stream>>>(x2b, Wa, ba, scores, rowsum, partial);
  tail_kernel<<<1, 1024, 0, stream>>>(scores, rowsum, partial, Wf, bf, out);
}